// Round 3
// baseline (574.298 us; speedup 1.0000x reference)
//
#include <hip/hip_runtime.h>
#include <hip/hip_bf16.h>
#include <stdint.h>

// Problem: LuongConcatAttention (additive attention), fp32 inputs.
//   dec (32,1024) f32; enc (32,2048,1024) f32; W_a (1024,2048) f32; v (1024) f32
//   out alpha (32,2048) f32 = softmax_s( sum_e tanh(decproj[b,e]+encproj[b,s,e]) * v[e] )
// Round 7: identical to round 6 (T3/T4 pipelined bf16 GEMM) EXCEPT the softmax
// launch now matches its 1024-thread body (round 6 launched 256 thr -> 3/4 of
// outputs never written + uninitialized wred[4..15]; absmax 1.03e-2 == max alpha).

typedef __bf16 bf16x8 __attribute__((ext_vector_type(8)));
typedef __bf16 bf16x2 __attribute__((ext_vector_type(2)));
typedef float floatx4 __attribute__((ext_vector_type(4)));
typedef unsigned short ushort_t;

#define M_TOT 65536
#define D_DIM 1024
#define WA_LD 2048
#define S_DIM 2048

#define VMCNT4 asm volatile("s_waitcnt vmcnt(4)" ::: "memory")
#define VMCNT0 asm volatile("s_waitcnt vmcnt(0)" ::: "memory")
#define BAR    __builtin_amdgcn_s_barrier()
#define SCHED0 __builtin_amdgcn_sched_barrier(0)

__device__ __forceinline__ unsigned int pack2(float a, float b) {
#if __has_builtin(__builtin_amdgcn_cvt_pk_bf16_f32)
    bf16x2 p = __builtin_amdgcn_cvt_pk_bf16_f32(a, b);
    return __builtin_bit_cast(unsigned int, p);
#else
    unsigned int ua = __float_as_uint(a), ub = __float_as_uint(b);
    ua += 0x7fffu + ((ua >> 16) & 1u);     // RNE (inputs finite)
    ub += 0x7fffu + ((ub >> 16) & 1u);
    return __builtin_amdgcn_perm(ub, ua, 0x07060302);  // {ub.hi16, ua.hi16}
#endif
}

// async global->LDS, 16B per lane; LDS dest = wave-uniform base + lane*16
__device__ __forceinline__ void gl16(const ushort_t* g, ushort_t* l) {
    __builtin_amdgcn_global_load_lds(
        (const __attribute__((address_space(1))) unsigned int*)g,
        (__attribute__((address_space(3))) unsigned int*)l,
        16, 0, 0);
}

// ---------------- kernel 0a: We (W_a[:,1024:]) -> bf16 [1024][1024] ----------------
__global__ __launch_bounds__(256) void convertW_kernel(
    const float* __restrict__ Wa, ushort_t* __restrict__ Web)
{
    const int e = blockIdx.x;
    const int k = threadIdx.x * 4;
    float4 wv = *(const float4*)(Wa + (size_t)e * WA_LD + D_DIM + k);
    uint2 pk = { pack2(wv.x, wv.y), pack2(wv.z, wv.w) };
    *(uint2*)(Web + (size_t)e * D_DIM + k) = pk;
}

// ---------------- kernel 0b: enc -> bf16, 67.1M elements, BW-bound ----------------
__global__ __launch_bounds__(256) void convert_enc_kernel(
    const float* __restrict__ in, ushort_t* __restrict__ out)
{
    size_t i = ((size_t)blockIdx.x * 256 + threadIdx.x) * 8;
    const size_t stride = (size_t)4096 * 256 * 8;
    for (int it = 0; it < 8; ++it, i += stride) {
        float4 a = *(const float4*)(in + i);
        float4 b = *(const float4*)(in + i + 4);
        uint4 pk = { pack2(a.x, a.y), pack2(a.z, a.w), pack2(b.x, b.y), pack2(b.z, b.w) };
        *(uint4*)(out + i) = pk;
    }
}

// ---------------- kernel 1: dec_proj[b][e] = sum_k dec[b,k] * W_a[e,k] ----------------
__global__ __launch_bounds__(256) void decproj_kernel(
    const float* __restrict__ dec,
    const float* __restrict__ Wa,
    float* __restrict__ dp)
{
    const int b    = blockIdx.y;
    const int wave = threadIdx.x >> 6;
    const int lane = threadIdx.x & 63;
    const int e    = blockIdx.x * 4 + wave;

    __shared__ float s_d[1024];
    for (int t = threadIdx.x; t < 1024; t += 256)
        s_d[t] = dec[b * 1024 + t];
    __syncthreads();

    const float* wrow = Wa + (size_t)e * WA_LD;   // Wd = W_a[:, :1024]
    float sum = 0.f;
    #pragma unroll
    for (int k0 = 0; k0 < 1024; k0 += 256) {
        float4 w = *(const float4*)(wrow + k0 + lane * 4);
        float4 d = *(const float4*)(&s_d[k0 + lane * 4]);
        sum += w.x * d.x + w.y * d.y + w.z * d.z + w.w * d.w;
    }
    #pragma unroll
    for (int msk = 1; msk < 64; msk <<= 1)
        sum += __shfl_xor(sum, msk, 64);
    if (lane == 0)
        dp[b * 1024 + e] = sum;
}

// ---- GEMM helpers (static buffer selection -> no runtime-indexed arrays) ----
__device__ __forceinline__ void stage_step(
    const ushort_t* Ag, const ushort_t* Bg, int k0,
    ushort_t* a0, ushort_t* a1, ushort_t* b0, ushort_t* b1)
{
    gl16(Ag + k0,              a0);
    gl16(Ag + k0 + 64 * D_DIM, a1);
    gl16(Bg + k0,              b0);
    gl16(Bg + k0 + 64 * D_DIM, b1);
}

__device__ __forceinline__ void compute_step(
    const ushort_t* Asb, const ushort_t* Bsb,
    const int* offA, const int* offB, floatx4 acc[4][4])
{
    bf16x8 af[4], bfr[4];
    #pragma unroll
    for (int i = 0; i < 4; ++i) af[i]  = *(const bf16x8*)(Asb + offA[i]);
    #pragma unroll
    for (int j = 0; j < 4; ++j) bfr[j] = *(const bf16x8*)(Bsb + offB[j]);
    #pragma unroll
    for (int i = 0; i < 4; ++i)
        #pragma unroll
        for (int j = 0; j < 4; ++j)
            acc[i][j] = __builtin_amdgcn_mfma_f32_16x16x32_bf16(af[i], bfr[j], acc[i][j], 0, 0, 0);
}

// ---------------- kernel 2: bf16 GEMM (enc @ We^T) + tanh + v-dot -> partial ----------
// 128x128x32 tile, 256 thr. Double-buffered LDS; prefetch next K-tile before compute;
// counted vmcnt(4) keeps prefetch in flight across raw s_barrier (T3/T4).
__global__ __launch_bounds__(256) void gemm_bf16_kernel(
    const ushort_t* __restrict__ A,      // enc bf16 [65536][1024]
    const ushort_t* __restrict__ Bw,     // We  bf16 [1024][1024]
    const float* __restrict__ v,
    const float* __restrict__ dp,
    float* __restrict__ partial)         // [8][65536]
{
    __shared__ ushort_t As[2][128 * 32];
    __shared__ ushort_t Bs[2][128 * 32];
    __shared__ float s_dec[128], s_v[128], s_score[128];

    const int tid  = threadIdx.x;
    const int lane = tid & 63;
    const int w    = tid >> 6;
    const int wm   = w >> 1;     // 0..1
    const int wn   = w & 1;      // 0..1
    const int r16  = lane & 15;
    const int q    = lane >> 4;

    // XCD swizzle: 8 n-blocks sharing one A-panel keep flat%8 fixed -> same XCD L2.
    const int flat    = blockIdx.y * 8 + blockIdx.x;
    const int n_block = (flat >> 3) & 7;
    const int m_block = (flat & 7) | ((flat >> 6) << 3);
    const int b_idx   = m_block >> 4;            // 2048/128 = 16 m-tiles per batch row

    if (tid < 128) {
        s_dec[tid] = dp[b_idx * 1024 + n_block * 128 + tid];
        s_v[tid]   = v[n_block * 128 + tid];
    }
    __syncthreads();    // publish s_dec/s_v (drains those loads; before any gl16 issue)

    // ---- staging addressing: linear LDS dest, pre-swizzled global source ----
    const int sr = (w << 4) + (lane >> 2);          // row 0..63 within half-tile
    const int fS = (sr & 3) ^ ((sr >> 2) & 1);
    const int sg = ((lane & 3) ^ fS) << 3;          // logical k-slot fetched (elements)
    const ushort_t* Ag = A  + (size_t)(m_block * 128 + sr) * D_DIM + sg;
    const ushort_t* Bg = Bw + (size_t)(n_block * 128 + sr) * D_DIM + sg;
    const int wbase0 = (w << 4) * 32;
    const int wbase1 = (64 + (w << 4)) * 32;

    // ---- fragment read offsets (swizzled) ----
    const int fR = (r16 & 3) ^ ((r16 >> 2) & 1);
    const int sl = (q ^ fR) << 3;
    int offA[4], offB[4];
    #pragma unroll
    for (int i = 0; i < 4; ++i) {
        offA[i] = (wm * 64 + i * 16 + r16) * 32 + sl;
        offB[i] = (wn * 64 + i * 16 + r16) * 32 + sl;
    }

    floatx4 acc[4][4] = {};

    // prologue: stage K-tile 0 into buf0
    stage_step(Ag, Bg, 0, &As[0][wbase0], &As[0][wbase1], &Bs[0][wbase0], &Bs[0][wbase1]);

    for (int t = 0; t < 30; t += 2) {
        // step A: prefetch t+1 -> buf1, compute buf0
        stage_step(Ag, Bg, (t + 1) * 32, &As[1][wbase0], &As[1][wbase1], &Bs[1][wbase0], &Bs[1][wbase1]);
        VMCNT4; BAR; SCHED0;
        compute_step(As[0], Bs[0], offA, offB, acc);
        SCHED0; BAR;
        // step B: prefetch t+2 -> buf0, compute buf1
        stage_step(Ag, Bg, (t + 2) * 32, &As[0][wbase0], &As[0][wbase1], &Bs[0][wbase0], &Bs[0][wbase1]);
        VMCNT4; BAR; SCHED0;
        compute_step(As[1], Bs[1], offA, offB, acc);
        SCHED0; BAR;
    }
    // epilogue steps t=30,31
    stage_step(Ag, Bg, 31 * 32, &As[1][wbase0], &As[1][wbase1], &Bs[1][wbase0], &Bs[1][wbase1]);
    VMCNT4; BAR; SCHED0;
    compute_step(As[0], Bs[0], offA, offB, acc);
    SCHED0; BAR;
    VMCNT0; BAR; SCHED0;
    compute_step(As[1], Bs[1], offA, offB, acc);

    // ---- epilogue: h = tanh(acc + dec), p[m] += h * v[n]; reduce over n ----
    float p[4][4] = {};
    #pragma unroll
    for (int j = 0; j < 4; ++j) {
        const int nl = wn * 64 + j * 16 + r16;    // C/D: col = lane&15 -> n
        const float dd = s_dec[nl];
        const float vv = s_v[nl];
        #pragma unroll
        for (int i = 0; i < 4; ++i) {
            #pragma unroll
            for (int r = 0; r < 4; ++r) {         // C/D: row = q*4+r -> m
                float x = acc[i][j][r] + dd;
                if (!(x > -8.f)) x = -8.f;        // NaN-proof clamp
                if (x > 8.f)     x = 8.f;
                float e2 = __expf(2.f * x);
                float h  = 1.f - 2.f * __builtin_amdgcn_rcpf(e2 + 1.f);
                p[i][r] += h * vv;
            }
        }
    }
    #pragma unroll
    for (int msk = 1; msk < 16; msk <<= 1) {
        #pragma unroll
        for (int i = 0; i < 4; ++i)
            #pragma unroll
            for (int r = 0; r < 4; ++r)
                p[i][r] += __shfl_xor(p[i][r], msk, 64);
    }
    __syncthreads();
    if (wn == 0 && r16 == 0) {
        #pragma unroll
        for (int i = 0; i < 4; ++i)
            #pragma unroll
            for (int r = 0; r < 4; ++r)
                s_score[wm * 64 + i * 16 + q * 4 + r] = p[i][r];
    }
    __syncthreads();
    if (wn == 1 && r16 == 0) {
        #pragma unroll
        for (int i = 0; i < 4; ++i)
            #pragma unroll
            for (int r = 0; r < 4; ++r)
                s_score[wm * 64 + i * 16 + q * 4 + r] += p[i][r];
    }
    __syncthreads();
    if (tid < 128)
        partial[(size_t)n_block * M_TOT + m_block * 128 + tid] = s_score[tid];
}

// ---------------- fallback GEMM (fp32 in-kernel pack) if workspace too small ----------
__global__ __launch_bounds__(256) void fused_gemm_fp32_kernel(
    const float* __restrict__ enc,
    const float* __restrict__ Wa,
    const float* __restrict__ v,
    const float* __restrict__ dp,
    float* __restrict__ partial)
{
    __shared__ unsigned short As[128 * 32];
    __shared__ unsigned short Bs[128 * 32];
    __shared__ float s_dec[128];
    __shared__ float s_v[128];
    __shared__ float s_score[128];

    const int tid  = threadIdx.x;
    const int lane = tid & 63;
    const int wave = tid >> 6;
    const int wm   = wave >> 1;
    const int wn   = wave & 1;

    const int flat    = blockIdx.y * 8 + blockIdx.x;
    const int n_block = (flat >> 3) & 7;
    const int m_block = (flat & 7) | ((flat >> 6) << 3);
    const int b_idx   = m_block >> 4;

    if (tid < 128) {
        s_dec[tid] = dp[b_idx * 1024 + n_block * 128 + tid];
        s_v[tid]   = v[n_block * 128 + tid];
    }

    const int r0  = tid >> 2;
    const int kk  = (tid & 3) * 8;
    const int r16 = lane & 15;
    const int q   = lane >> 4;

    const float* A_base = enc + (size_t)m_block * 128 * D_DIM;
    const float* B_base = Wa + (size_t)n_block * 128 * WA_LD + D_DIM;

    floatx4 acc[4][4] = {};

    for (int k0 = 0; k0 < 1024; k0 += 32) {
        float4 a0l = *(const float4*)(A_base + (size_t)r0        * D_DIM + k0 + kk);
        float4 a0h = *(const float4*)(A_base + (size_t)r0        * D_DIM + k0 + kk + 4);
        float4 a1l = *(const float4*)(A_base + (size_t)(r0 + 64) * D_DIM + k0 + kk);
        float4 a1h = *(const float4*)(A_base + (size_t)(r0 + 64) * D_DIM + k0 + kk + 4);
        float4 b0l = *(const float4*)(B_base + (size_t)r0        * WA_LD + k0 + kk);
        float4 b0h = *(const float4*)(B_base + (size_t)r0        * WA_LD + k0 + kk + 4);
        float4 b1l = *(const float4*)(B_base + (size_t)(r0 + 64) * WA_LD + k0 + kk);
        float4 b1h = *(const float4*)(B_base + (size_t)(r0 + 64) * WA_LD + k0 + kk + 4);
        uint4 pa0 = { pack2(a0l.x, a0l.y), pack2(a0l.z, a0l.w), pack2(a0h.x, a0h.y), pack2(a0h.z, a0h.w) };
        uint4 pa1 = { pack2(a1l.x, a1l.y), pack2(a1l.z, a1l.w), pack2(a1h.x, a1h.y), pack2(a1h.z, a1h.w) };
        uint4 pb0 = { pack2(b0l.x, b0l.y), pack2(b0l.z, b0l.w), pack2(b0h.x, b0h.y), pack2(b0h.z, b0h.w) };
        uint4 pb1 = { pack2(b1l.x, b1l.y), pack2(b1l.z, b1l.w), pack2(b1h.x, b1h.y), pack2(b1h.z, b1h.w) };
        __syncthreads();
        *(uint4*)&As[r0        * 32 + kk] = pa0;
        *(uint4*)&As[(r0 + 64) * 32 + kk] = pa1;
        *(uint4*)&Bs[r0        * 32 + kk] = pb0;
        *(uint4*)&Bs[(r0 + 64) * 32 + kk] = pb1;
        __syncthreads();

        bf16x8 af[4], bfr[4];
        #pragma unroll
        for (int i = 0; i < 4; ++i)
            af[i] = *(const bf16x8*)&As[(wm * 64 + i * 16 + r16) * 32 + q * 8];
        #pragma unroll
        for (int j = 0; j < 4; ++j)
            bfr[j] = *(const bf16x8*)&Bs[(wn * 64 + j * 16 + r16) * 32 + q * 8];
        #pragma unroll
        for (int i = 0; i < 4; ++i)
            #pragma unroll
            for (int j = 0; j < 4; ++j)
                acc[i][j] = __builtin_amdgcn_mfma_f32_16x16x32_bf16(af[i], bfr[j], acc[i][j], 0, 0, 0);
    }

    float p[4][4] = {};
    #pragma unroll
    for (int j = 0; j < 4; ++j) {
        const int nl = wn * 64 + j * 16 + r16;
        const float dd = s_dec[nl];
        const float vv = s_v[nl];
        #pragma unroll
        for (int i = 0; i < 4; ++i) {
            #pragma unroll
            for (int r = 0; r < 4; ++r) {
                float x = acc[i][j][r] + dd;
                if (!(x > -8.f)) x = -8.f;
                if (x > 8.f)     x = 8.f;
                float e2 = __expf(2.f * x);
                float h  = 1.f - 2.f * __builtin_amdgcn_rcpf(e2 + 1.f);
                p[i][r] += h * vv;
            }
        }
    }
    #pragma unroll
    for (int msk = 1; msk < 16; msk <<= 1) {
        #pragma unroll
        for (int i = 0; i < 4; ++i)
            #pragma unroll
            for (int r = 0; r < 4; ++r)
                p[i][r] += __shfl_xor(p[i][r], msk, 64);
    }
    __syncthreads();
    if (wn == 0 && r16 == 0) {
        #pragma unroll
        for (int i = 0; i < 4; ++i)
            #pragma unroll
            for (int r = 0; r < 4; ++r)
                s_score[wm * 64 + i * 16 + q * 4 + r] = p[i][r];
    }
    __syncthreads();
    if (wn == 1 && r16 == 0) {
        #pragma unroll
        for (int i = 0; i < 4; ++i)
            #pragma unroll
            for (int r = 0; r < 4; ++r)
                s_score[wm * 64 + i * 16 + q * 4 + r] += p[i][r];
    }
    __syncthreads();
    if (tid < 128)
        partial[(size_t)n_block * M_TOT + m_block * 128 + tid] = s_score[tid];
}

// ---------------- kernel 3: softmax over s per batch row (1024 thr) ----------------
__global__ __launch_bounds__(1024) void softmax_kernel(
    const float* __restrict__ partial,   // [8][65536]
    float* __restrict__ out)             // [32][2048] f32
{
    const int b = blockIdx.x;
    const int tid = threadIdx.x;
    const int wv = tid >> 6;
    __shared__ float wred[16];

    float sc[2];
    float mx = -1e30f;
    #pragma unroll
    for (int ii = 0; ii < 2; ++ii) {
        const int s = tid + ii * 1024;
        float sum = 0.f;
        #pragma unroll
        for (int pp = 0; pp < 8; ++pp)
            sum += partial[(size_t)pp * M_TOT + b * S_DIM + s];
        sc[ii] = sum;
        mx = fmaxf(mx, sum);
    }
    #pragma unroll
    for (int msk = 1; msk < 64; msk <<= 1) mx = fmaxf(mx, __shfl_xor(mx, msk, 64));
    if ((tid & 63) == 0) wred[wv] = mx;
    __syncthreads();
    #pragma unroll
    for (int k = 0; k < 16; ++k) mx = fmaxf(mx, wred[k]);
    __syncthreads();

    float ex[2];
    float tot = 0.f;
    #pragma unroll
    for (int ii = 0; ii < 2; ++ii) { ex[ii] = __expf(sc[ii] - mx); tot += ex[ii]; }
    #pragma unroll
    for (int msk = 1; msk < 64; msk <<= 1) tot += __shfl_xor(tot, msk, 64);
    if ((tid & 63) == 0) wred[wv] = tot;
    __syncthreads();
    tot = 0.f;
    #pragma unroll
    for (int k = 0; k < 16; ++k) tot += wred[k];
    const float inv = 1.f / tot;
    #pragma unroll
    for (int ii = 0; ii < 2; ++ii)
        out[b * S_DIM + tid + ii * 1024] = ex[ii] * inv;
}

extern "C" void kernel_launch(void* const* d_in, const int* in_sizes, int n_in,
                              void* d_out, int out_size, void* d_ws, size_t ws_size,
                              hipStream_t stream) {
    (void)in_sizes; (void)n_in; (void)out_size;
    const float* dec = (const float*)d_in[0];
    const float* enc = (const float*)d_in[1];
    const float* Wa  = (const float*)d_in[2];
    const float* v   = (const float*)d_in[3];
    float* out = (float*)d_out;

    float* dp      = (float*)d_ws;        // 32*1024 floats   = 128 KB
    float* partial = dp + 32 * 1024;      // 8*65536 floats   = 2 MB

    const size_t NEED = (size_t)(32 * 1024 + 8 * 65536) * 4
                      + (size_t)67108864 * 2            // enc bf16
                      + (size_t)1048576 * 2;            // We bf16

    if (ws_size >= NEED) {
        ushort_t* encb = (ushort_t*)(partial + 8 * 65536);
        ushort_t* Web  = encb + 67108864;
        convertW_kernel<<<dim3(1024), 256, 0, stream>>>(Wa, Web);
        convert_enc_kernel<<<dim3(4096), 256, 0, stream>>>(enc, encb);
        decproj_kernel<<<dim3(256, 32), 256, 0, stream>>>(dec, Wa, dp);
        gemm_bf16_kernel<<<dim3(8, 512), 256, 0, stream>>>(encb, Web, v, dp, partial);
    } else {
        decproj_kernel<<<dim3(256, 32), 256, 0, stream>>>(dec, Wa, dp);
        fused_gemm_fp32_kernel<<<dim3(8, 512), 256, 0, stream>>>(enc, Wa, v, dp, partial);
    }
    softmax_kernel<<<32, 1024, 0, stream>>>(partial, out);
}